// Round 3
// baseline (326.909 us; speedup 1.0000x reference)
//
#include <hip/hip_runtime.h>
#include <math.h>

#define NPTS    131072
#define FEAT    64
#define KCLUS   2048
#define CHUNKC  256      // clusters staged per LDS chunk (== blockDim)
#define NCHUNK  (KCLUS / CHUNKC)   // 8
#define PPW     32       // points per wave for pass 2 (2 MFMA row-tiles)
#define WPB     4        // waves per 256-thread block (wave = 64 on CDNA!)
#define PPB     (PPW * WPB)   // 128 points per block
#define CANDC   10       // per-lane register candidate slots

typedef __attribute__((ext_vector_type(8))) short frag_ab;   // 8 bf16
typedef __attribute__((ext_vector_type(4))) float frag_cd;   // 4 fp32 acc

// fp32 -> bf16 RNE
__device__ __forceinline__ short f2bf(float f) {
    unsigned u = __float_as_uint(f);
    u += 0x7FFFu + ((u >> 16) & 1u);
    return (short)(u >> 16);
}

// Exact fp32 distance term (cn - 2 x.c): IDENTICAL single-chain FMA order to
// prior proven rounds (matches numpy argmin on this data, absmax 0 x9).
__device__ __forceinline__ float exact_dist(const float* __restrict__ x,
                                            const float* __restrict__ c,
                                            float cnv, int p, int kk) {
    const float4* xr4 = (const float4*)&x[(size_t)p * FEAT];
    const float4* cr4 = (const float4*)&c[(size_t)kk * FEAT];
    float s = 0.f;
#pragma unroll
    for (int j = 0; j < 16; ++j) {
        float4 a4 = xr4[j], b4 = cr4[j];
        s = fmaf(a4.x, b4.x, s); s = fmaf(a4.y, b4.y, s);
        s = fmaf(a4.z, b4.z, s); s = fmaf(a4.w, b4.w, s);
    }
    return fmaf(-2.f, s, cnv);
}

// ---------------------------------------------------------------------------
// cprep: exact fp32 cnorm, cbs_t = bf16(-2c) part-major [part=f/8][k][8]
// (proven conflict-free + correct B layout), cmax = max||c||.  UNCHANGED.
// ---------------------------------------------------------------------------
__global__ void cprep_kernel(const float* __restrict__ c, float* __restrict__ cnorm,
                             short* __restrict__ cbs_t, float* __restrict__ cmax) {
    int k = blockIdx.x * blockDim.x + threadIdx.x;
    if (k >= KCLUS) return;
    const float4* row = (const float4*)&c[k * FEAT];
    float s = 0.f;
#pragma unroll
    for (int j = 0; j < 16; ++j) {
        float4 v = row[j];
        s = fmaf(v.x, v.x, s); s = fmaf(v.y, v.y, s);
        s = fmaf(v.z, v.z, s); s = fmaf(v.w, v.w, s);
        short4 b;
        b.x = f2bf(-2.f * v.x); b.y = f2bf(-2.f * v.y);
        b.z = f2bf(-2.f * v.z); b.w = f2bf(-2.f * v.w);
        *(short4*)&cbs_t[((size_t)(j >> 1) * KCLUS + k) * 8 + (j & 1) * 4] = b;
    }
    cnorm[k] = s;
    atomicMax((int*)cmax, __float_as_int(sqrtf(s)));  // positive: int-max == float-max
}

// Prefetch one 256-cluster chunk into registers (8 x 16B global loads + norm).
// r0-proven staging path -- the two gload_lds variants (r1/r2) both regressed.
__device__ __forceinline__ void load_chunk(const short* __restrict__ cbs_t,
                                           const float* __restrict__ cnorm,
                                           int k0, int tid,
                                           frag_ab pre[8], float* cnpre) {
#pragma unroll
    for (int p8 = 0; p8 < 8; ++p8)
        pre[p8] = *(const frag_ab*)&cbs_t[((size_t)p8 * KCLUS + k0 + tid) * 8];
    *cnpre = cnorm[k0 + tid];
}

// ---------------------------------------------------------------------------
// Assign, r3: r0-proven structure with PAIR-COOPERATIVE PASS 1.
// Pass 1: waves w,w^1 cooperate -- each computes 64 rows (4 row-tiles from the
// pair base) x its column-HALF (h = wv&1) of every chunk.  Same MFMA count per
// wave, but each B-fragment ds_read feeds 4 row-tiles instead of 2 -> pass-1
// LDS-B reads halve, ct-loop overhead halves.  Per-lane minima exchanged with
// the partner wave through csh (free between passes), then combined.
// Pass 2 / thresholds / refine / fallback: byte-identical r0 logic on the
// A4[h*2+rt] subset.  Every (row,k) acc is produced by exactly one wave with
// the identical instruction sequence as r0 -> same capture set -> absmax 0.
// ---------------------------------------------------------------------------
__global__ __launch_bounds__(256) void assign_kernel(
    const float* __restrict__ x, const float* __restrict__ c,
    const short* __restrict__ cbs_t, const float* __restrict__ cnorm,
    const float* __restrict__ cmaxp,
    float* __restrict__ out_assign, unsigned short* __restrict__ a16)
{
    __shared__ short csh[8 * CHUNKC * 8];   // 32 KB part-major staging
    __shared__ float cnsh[CHUNKC];          // 1 KB

    const int tid = threadIdx.x, wv = tid >> 6, lane = tid & 63;
    const int col = lane & 15, q = lane >> 4;
    const int pt0  = blockIdx.x * PPB + wv * PPW;         // pass-2 rows (32)
    const int pt0p = blockIdx.x * PPB + (wv >> 1) * 64;   // pass-1 pair rows (64)
    const int h = wv & 1;                                  // pass-1 column half

    // A-frags for the PAIR's 4 row-tiles (proven layout) + inline row norms
    // (proven butterfly over lane bits 16/32).  Pass 2 uses tiles h*2, h*2+1
    // (== rows [pt0, pt0+32), identical data to r0's A[0..1]).
    frag_ab A4[4][2];
    float nrm4[4];
#pragma unroll
    for (int rt = 0; rt < 4; ++rt) {
        float ps = 0.f;
#pragma unroll
        for (int kh = 0; kh < 2; ++kh) {
            const float4* xp = (const float4*)&x[(size_t)(pt0p + rt * 16 + col) * FEAT + kh * 32 + q * 8];
            float4 v0 = xp[0], v1 = xp[1];
            frag_ab a;
            a[0] = f2bf(v0.x); a[1] = f2bf(v0.y); a[2] = f2bf(v0.z); a[3] = f2bf(v0.w);
            a[4] = f2bf(v1.x); a[5] = f2bf(v1.y); a[6] = f2bf(v1.z); a[7] = f2bf(v1.w);
            A4[rt][kh] = a;
            ps = fmaf(v0.x, v0.x, ps); ps = fmaf(v0.y, v0.y, ps);
            ps = fmaf(v0.z, v0.z, ps); ps = fmaf(v0.w, v0.w, ps);
            ps = fmaf(v1.x, v1.x, ps); ps = fmaf(v1.y, v1.y, ps);
            ps = fmaf(v1.z, v1.z, ps); ps = fmaf(v1.w, v1.w, ps);
        }
        ps += __shfl_xor(ps, 16);
        ps += __shfl_xor(ps, 32);
        nrm4[rt] = sqrtf(ps);
    }

    float m4[4][4];
#pragma unroll
    for (int rt = 0; rt < 4; ++rt)
#pragma unroll
        for (int r = 0; r < 4; ++r) m4[rt][r] = INFINITY;

    frag_ab pre[8];
    float   cnpre;

    // ------------------- PASS 1: approx min, pair-cooperative --------------
    load_chunk(cbs_t, cnorm, 0, tid, pre, &cnpre);
    for (int c8 = 0; c8 < NCHUNK; ++c8) {
        __syncthreads();
#pragma unroll
        for (int p8 = 0; p8 < 8; ++p8)
            *(frag_ab*)&csh[(p8 * CHUNKC + tid) * 8] = pre[p8];
        cnsh[tid] = cnpre;
        __syncthreads();
        if (c8 < NCHUNK - 1)
            load_chunk(cbs_t, cnorm, (c8 + 1) * CHUNKC, tid, pre, &cnpre);  // overlaps compute

#pragma unroll 4
        for (int ct = 0; ct < CHUNKC / 32; ++ct) {          // 8 col-groups (own half)
            const int lc = h * 128 + ct * 16 + col;
            frag_ab b0 = *(const frag_ab*)&csh[(q * CHUNKC + lc) * 8];
            frag_ab b1 = *(const frag_ab*)&csh[((4 + q) * CHUNKC + lc) * 8];
            const float cnv = cnsh[lc];
#pragma unroll
            for (int rt = 0; rt < 4; ++rt) {
                frag_cd acc = {cnv, cnv, cnv, cnv};
                acc = __builtin_amdgcn_mfma_f32_16x16x32_bf16(A4[rt][0], b0, acc, 0, 0, 0);
                acc = __builtin_amdgcn_mfma_f32_16x16x32_bf16(A4[rt][1], b1, acc, 0, 0, 0);
                m4[rt][0] = fminf(m4[rt][0], acc[0]);
                m4[rt][1] = fminf(m4[rt][1], acc[1]);
                m4[rt][2] = fminf(m4[rt][2], acc[2]);
                m4[rt][3] = fminf(m4[rt][3], acc[3]);
            }
        }
    }

    // ----- exchange per-lane minima with partner wave via csh (now free) ---
    __syncthreads();                       // all waves done reading chunk 7
    {
        float* mx = (float*)csh;           // 256 threads x 16 floats = 16 KB
#pragma unroll
        for (int rt = 0; rt < 4; ++rt) {
            float4 v = { m4[rt][0], m4[rt][1], m4[rt][2], m4[rt][3] };
            *(float4*)&mx[tid * 16 + rt * 4] = v;
        }
    }
    __syncthreads();
    {
        const float* mx = (const float*)csh;
        const int ptid = tid ^ 64;         // partner wave, same lane
#pragma unroll
        for (int rt = 0; rt < 4; ++rt) {
            float4 v = *(const float4*)&mx[ptid * 16 + rt * 4];
            m4[rt][0] = fminf(m4[rt][0], v.x);
            m4[rt][1] = fminf(m4[rt][1], v.y);
            m4[rt][2] = fminf(m4[rt][2], v.z);
            m4[rt][3] = fminf(m4[rt][3], v.w);
        }
    }

    // Threshold: m~ + 0.034*||x||*cmax >= m~ + 2*eps_bf16 (proven margin).
    // Operates on this wave's pass-2 tiles: absolute tile art = h*2 + rt.
    const float cmax = *cmaxp;
    float t[2][4];
#pragma unroll
    for (int rt = 0; rt < 2; ++rt) {
        const int art = h * 2 + rt;
#pragma unroll
        for (int r = 0; r < 4; ++r) {
            float mm = m4[art][r];
            mm = fminf(mm, __shfl_xor(mm, 1));
            mm = fminf(mm, __shfl_xor(mm, 2));
            mm = fminf(mm, __shfl_xor(mm, 4));
            mm = fminf(mm, __shfl_xor(mm, 8));
            float xnp = __shfl(nrm4[art], q * 4 + r);   // lane q*4+r holds that row's norm
            t[rt][r] = mm + 0.034f * xnp * cmax;
        }
    }

    // ------------------- PASS 2: per-lane register capture (r0 verbatim) ---
    unsigned codes[CANDC];
    int ccnt = 0;

    load_chunk(cbs_t, cnorm, 0, tid, pre, &cnpre);
    for (int c8 = 0; c8 < NCHUNK; ++c8) {
        __syncthreads();
#pragma unroll
        for (int p8 = 0; p8 < 8; ++p8)
            *(frag_ab*)&csh[(p8 * CHUNKC + tid) * 8] = pre[p8];
        cnsh[tid] = cnpre;
        __syncthreads();
        if (c8 < NCHUNK - 1)
            load_chunk(cbs_t, cnorm, (c8 + 1) * CHUNKC, tid, pre, &cnpre);

        const int k0 = c8 * CHUNKC;
#pragma unroll 2
        for (int ct = 0; ct < CHUNKC / 16; ++ct) {
            const int lc = ct * 16 + col;
            frag_ab b0 = *(const frag_ab*)&csh[(q * CHUNKC + lc) * 8];
            frag_ab b1 = *(const frag_ab*)&csh[((4 + q) * CHUNKC + lc) * 8];
            const float cnv = cnsh[lc];
            const int kk = k0 + lc;
#pragma unroll
            for (int rt = 0; rt < 2; ++rt) {
                frag_cd acc = {cnv, cnv, cnv, cnv};
                acc = __builtin_amdgcn_mfma_f32_16x16x32_bf16(A4[h * 2 + rt][0], b0, acc, 0, 0, 0);
                acc = __builtin_amdgcn_mfma_f32_16x16x32_bf16(A4[h * 2 + rt][1], b1, acc, 0, 0, 0);
#pragma unroll
                for (int r = 0; r < 4; ++r) {
                    if (acc[r] <= t[rt][r]) {   // rare
                        unsigned code = ((unsigned)(rt * 16 + q * 4 + r) << 11) | (unsigned)kk;
#pragma unroll
                        for (int s = 0; s < CANDC; ++s)   // register-file push
                            if (s == ccnt) codes[s] = code;
                        ccnt++;
                    }
                }
            }
        }
    }

    // ------------------- exact refine (per-lane, registers) ----------------
    const bool anyovf = __any(ccnt > CANDC);

    if (!anyovf) {
        float bestd[2][4];
        int   bestk[2][4];
#pragma unroll
        for (int rt = 0; rt < 2; ++rt)
#pragma unroll
            for (int r = 0; r < 4; ++r) { bestd[rt][r] = INFINITY; bestk[rt][r] = 0x7fffffff; }

        for (int i = 0; i < CANDC; ++i) {
            if (i < ccnt) {
                unsigned code = codes[i];
                int pl = (int)(code >> 11), kk = (int)(code & 2047u);
                float e = exact_dist(x, c, cnorm[kk], pt0 + pl, kk);
                int crt = pl >> 4, cr = pl & 3;
#pragma unroll
                for (int rt = 0; rt < 2; ++rt)
#pragma unroll
                    for (int r = 0; r < 4; ++r)
                        if (crt == rt && cr == r &&
                            (e < bestd[rt][r] || (e == bestd[rt][r] && kk < bestk[rt][r]))) {
                            bestd[rt][r] = e; bestk[rt][r] = kk;
                        }
            }
        }

        // Proven cross-lane (d,k) reduce + col==0 writes (float4 + ushort4).
#pragma unroll
        for (int rt = 0; rt < 2; ++rt) {
#pragma unroll
            for (int r = 0; r < 4; ++r) {
                float bd = bestd[rt][r]; int bk = bestk[rt][r];
#pragma unroll
                for (int mask = 1; mask <= 8; mask <<= 1) {
                    float od = __shfl_xor(bd, mask);
                    int   ok = __shfl_xor(bk, mask);
                    if (od < bd || (od == bd && ok < bk)) { bd = od; bk = ok; }
                }
                bestd[rt][r] = bd; bestk[rt][r] = bk;
            }
            if (col == 0) {
                float4 w = { (float)bestk[rt][0], (float)bestk[rt][1],
                             (float)bestk[rt][2], (float)bestk[rt][3] };
                *(float4*)&out_assign[pt0 + rt * 16 + q * 4] = w;
                ushort4 u = { (unsigned short)bestk[rt][0], (unsigned short)bestk[rt][1],
                              (unsigned short)bestk[rt][2], (unsigned short)bestk[rt][3] };
                *(ushort4*)&a16[pt0 + rt * 16 + q * 4] = u;
            }
        }
    } else {
        // Overflow (rare): whole-wave fully-exact argmin, no thresholds.
        for (int pp = 0; pp < PPW; ++pp) {
            const int p = pt0 + pp;
            float bd = INFINITY; int bk = 0x7fffffff;
            for (int kk = lane; kk < KCLUS; kk += 64) {
                float e = exact_dist(x, c, cnorm[kk], p, kk);
                if (e < bd || (e == bd && kk < bk)) { bd = e; bk = kk; }
            }
#pragma unroll
            for (int mask = 1; mask <= 32; mask <<= 1) {
                float od = __shfl_xor(bd, mask);
                int   ok = __shfl_xor(bk, mask);
                if (od < bd || (od == bd && ok < bk)) { bd = od; bk = ok; }
            }
            if (lane == 0) {
                out_assign[p] = (float)bk;
                a16[p] = (unsigned short)bk;
            }
        }
    }
}

// ---------------------------------------------------------------------------
// Scatter (proven, verbatim): block (cg, slice) owns clusters [8cg,8cg+8)
// over point slice [slice*16384, +16384). Ballot-collect, per-wave LDS
// accumulate, 8 atomic rows per block.
// ---------------------------------------------------------------------------
__global__ void scatter_kernel(const float* __restrict__ x,
                               const unsigned short* __restrict__ a16,
                               float* __restrict__ sums, int* __restrict__ counts) {
    __shared__ float wsum[4][8][64];   // 8 KB, per-wave private
    __shared__ int   wcnt[4][8];

    const int tid = threadIdx.x, wv = tid >> 6, lane = tid & 63;
    const int c0 = blockIdx.x * 8;

    for (int idx = tid; idx < 4 * 8 * 64; idx += 256) ((float*)wsum)[idx] = 0.f;
    if (tid < 32) ((int*)wcnt)[tid] = 0;
    __syncthreads();

    const int base = blockIdx.y * 16384 + wv * 4096;
#pragma unroll 1
    for (int it = 0; it < 64; ++it) {
        const int pbase = base + it * 64;
        int a = (int)a16[pbase + lane];                    // coalesced 128B
        unsigned long long mask = __ballot(a >= c0 && a < c0 + 8);
        while (mask) {
            int j = __ffsll((long long)mask) - 1;
            mask &= mask - 1;
            int cl = __shfl(a, j) - c0;
            float xv = x[(size_t)(pbase + j) * FEAT + lane];  // coalesced 256B row
            wsum[wv][cl][lane] += xv;                         // own slice: no race
            if (lane == 0) wcnt[wv][cl] += 1;
        }
    }
    __syncthreads();

    for (int idx = tid; idx < 512; idx += 256) {
        int cl = idx >> 6, ln = idx & 63;
        float s = wsum[0][cl][ln] + wsum[1][cl][ln] + wsum[2][cl][ln] + wsum[3][cl][ln];
        atomicAdd(&sums[(size_t)(c0 + cl) * FEAT + ln], s);
    }
    if (tid < 8) {
        int cc = wcnt[0][tid] + wcnt[1][tid] + wcnt[2][tid] + wcnt[3][tid];
        if (cc) atomicAdd(&counts[c0 + tid], cc);
    }
}

__global__ void update_kernel(const float* __restrict__ c,
                              const float* __restrict__ sums,
                              const int* __restrict__ counts,
                              float* __restrict__ out_upd) {
    int i = blockIdx.x * blockDim.x + threadIdx.x;
    if (i < KCLUS * FEAT) {
        int   k   = i >> 6;
        float cv  = c[i];
        int   cnt = counts[k];
        float nc  = (cnt > 0) ? (sums[i] / (float)cnt) : cv;
        out_upd[i] = 0.99f * cv + 0.01f * nc;
    }
}

extern "C" void kernel_launch(void* const* d_in, const int* in_sizes, int n_in,
                              void* d_out, int out_size, void* d_ws, size_t ws_size,
                              hipStream_t stream) {
    const float* x = (const float*)d_in[0];
    const float* c = (const float*)d_in[1];

    float* out        = (float*)d_out;
    float* out_assign = out;          // [0, N): assignments as float
    float* out_upd    = out + NPTS;   // [N, N + K*FEAT)

    // Workspace ~1.06 MB.
    char* ws = (char*)d_ws;
    constexpr size_t O_CNORM = 0;                       // 8 KB
    constexpr size_t O_CBS   = 8192;                    // 256 KB
    constexpr size_t O_ZERO  = 8192 + 262144;           // 270336
    constexpr size_t O_CMAX  = O_ZERO;                  // 64 B
    constexpr size_t O_SUMS  = O_ZERO + 64;             // 512 KB
    constexpr size_t O_CNTS  = O_SUMS + 524288;         // 8 KB
    constexpr size_t ZERO_LEN = 64 + 524288 + 8192;     // 532544
    constexpr size_t O_A16   = O_ZERO + ZERO_LEN;       // 802880, 256 KB

    float*    cnorm  = (float*)(ws + O_CNORM);
    short*    cbs_t  = (short*)(ws + O_CBS);
    float*    cmax   = (float*)(ws + O_CMAX);
    float*    sums   = (float*)(ws + O_SUMS);
    int*      counts = (int*)(ws + O_CNTS);
    unsigned short* a16 = (unsigned short*)(ws + O_A16);

    hipMemsetAsync(ws + O_ZERO, 0, ZERO_LEN, stream);

    cprep_kernel<<<KCLUS / 256, 256, 0, stream>>>(c, cnorm, cbs_t, cmax);
    // 4 waves/block x 32 pts/wave = 128 pts/block -> grid 1024 (4 blocks/CU)
    assign_kernel<<<NPTS / PPB, 256, 0, stream>>>(x, c, cbs_t, cnorm, cmax,
                                                  out_assign, a16);
    scatter_kernel<<<dim3(KCLUS / 8, 8), 256, 0, stream>>>(x, a16, sums, counts);
    update_kernel<<<(KCLUS * FEAT) / 256, 256, 0, stream>>>(c, sums, counts, out_upd);
}

// Round 4
// 296.645 us; speedup vs baseline: 1.1020x; 1.1020x over previous
//
#include <hip/hip_runtime.h>
#include <math.h>

#define NPTS    131072
#define FEAT    64
#define KCLUS   2048
#define CHUNKC  256      // clusters staged per LDS chunk (== blockDim)
#define NCHUNK  (KCLUS / CHUNKC)   // 8
#define PPW     32       // points per wave for pass 2 (2 MFMA row-tiles)
#define WPB     4        // waves per 256-thread block (wave = 64 on CDNA!)
#define PPB     (PPW * WPB)   // 128 points per block
#define CANDC   10       // per-lane register candidate slots

typedef __attribute__((ext_vector_type(8))) short frag_ab;   // 8 bf16
typedef __attribute__((ext_vector_type(4))) float frag_cd;   // 4 fp32 acc

// fp32 -> bf16 RNE
__device__ __forceinline__ short f2bf(float f) {
    unsigned u = __float_as_uint(f);
    u += 0x7FFFu + ((u >> 16) & 1u);
    return (short)(u >> 16);
}

// Exact fp32 distance term (cn - 2 x.c): IDENTICAL single-chain FMA order to
// prior proven rounds (matches numpy argmin on this data, absmax 0 x10).
__device__ __forceinline__ float exact_dist(const float* __restrict__ x,
                                            const float* __restrict__ c,
                                            float cnv, int p, int kk) {
    const float4* xr4 = (const float4*)&x[(size_t)p * FEAT];
    const float4* cr4 = (const float4*)&c[(size_t)kk * FEAT];
    float s = 0.f;
#pragma unroll
    for (int j = 0; j < 16; ++j) {
        float4 a4 = xr4[j], b4 = cr4[j];
        s = fmaf(a4.x, b4.x, s); s = fmaf(a4.y, b4.y, s);
        s = fmaf(a4.z, b4.z, s); s = fmaf(a4.w, b4.w, s);
    }
    return fmaf(-2.f, s, cnv);
}

// ---------------------------------------------------------------------------
// cprep: exact fp32 cnorm, cbs_t = bf16(-2c) part-major [part=f/8][k][8]
// (proven conflict-free + correct B layout), cmax = max||c||.  UNCHANGED.
// ---------------------------------------------------------------------------
__global__ void cprep_kernel(const float* __restrict__ c, float* __restrict__ cnorm,
                             short* __restrict__ cbs_t, float* __restrict__ cmax) {
    int k = blockIdx.x * blockDim.x + threadIdx.x;
    if (k >= KCLUS) return;
    const float4* row = (const float4*)&c[k * FEAT];
    float s = 0.f;
#pragma unroll
    for (int j = 0; j < 16; ++j) {
        float4 v = row[j];
        s = fmaf(v.x, v.x, s); s = fmaf(v.y, v.y, s);
        s = fmaf(v.z, v.z, s); s = fmaf(v.w, v.w, s);
        short4 b;
        b.x = f2bf(-2.f * v.x); b.y = f2bf(-2.f * v.y);
        b.z = f2bf(-2.f * v.z); b.w = f2bf(-2.f * v.w);
        *(short4*)&cbs_t[((size_t)(j >> 1) * KCLUS + k) * 8 + (j & 1) * 4] = b;
    }
    cnorm[k] = s;
    atomicMax((int*)cmax, __float_as_int(sqrtf(s)));  // positive: int-max == float-max
}

// Prefetch one 256-cluster chunk into registers (8 x 16B global loads + norm).
// r0-proven staging path -- the two gload_lds variants (r1/r2) both regressed.
__device__ __forceinline__ void load_chunk(const short* __restrict__ cbs_t,
                                           const float* __restrict__ cnorm,
                                           int k0, int tid,
                                           frag_ab pre[8], float* cnpre) {
#pragma unroll
    for (int p8 = 0; p8 < 8; ++p8)
        pre[p8] = *(const frag_ab*)&cbs_t[((size_t)p8 * KCLUS + k0 + tid) * 8];
    *cnpre = cnorm[k0 + tid];
}

// ---------------------------------------------------------------------------
// Assign, r4 = r3 (pair-cooperative pass 1, absmax-0-proven) with the two
// artifacts removed:
//  (a) NO runtime indexing of A4/nrm4/m4 in pass 2: a wave-uniform h-branch
//      copies the wave's two tiles into A2/nrm2/m2 with literal indices
//      (r3's A4[h*2+rt] sent the whole array to scratch: 128 B/thread =
//      exactly the observed +32.7 MB WRITE_SIZE).
//  (b) min-exchange through csh in TRANSPOSED scalar layout
//      mx[(slot)*256 + tid]: lane-consecutive, conflict-free (r3's
//      tid*64B-stride float4s caused the 589k bank-conflict cycles).
// Pass 1: waves w,w^1 cooperate -- each computes 64 rows (4 row-tiles) x its
// column-half of every chunk -> pass-1 B ds_reads and ct-loop overhead halve.
// Pass 2 / thresholds / refine / fallback: byte-identical r0 logic.
// ---------------------------------------------------------------------------
__global__ __launch_bounds__(256) void assign_kernel(
    const float* __restrict__ x, const float* __restrict__ c,
    const short* __restrict__ cbs_t, const float* __restrict__ cnorm,
    const float* __restrict__ cmaxp,
    float* __restrict__ out_assign, unsigned short* __restrict__ a16)
{
    __shared__ short csh[8 * CHUNKC * 8];   // 32 KB part-major staging
    __shared__ float cnsh[CHUNKC];          // 1 KB

    const int tid = threadIdx.x, wv = tid >> 6, lane = tid & 63;
    const int col = lane & 15, q = lane >> 4;
    const int pt0  = blockIdx.x * PPB + wv * PPW;         // pass-2 rows (32)
    const int pt0p = blockIdx.x * PPB + (wv >> 1) * 64;   // pass-1 pair rows (64)
    const int h = wv & 1;                                  // pass-1 column half

    // A-frags for the PAIR's 4 row-tiles (proven layout) + inline row norms
    // (proven butterfly over lane bits 16/32).  Tile art = h*2+rt covers rows
    // pt0p + art*16 == pt0 + rt*16, i.e. exactly r0's A[rt] data.
    frag_ab A4[4][2];
    float nrm4[4];
#pragma unroll
    for (int rt = 0; rt < 4; ++rt) {
        float ps = 0.f;
#pragma unroll
        for (int kh = 0; kh < 2; ++kh) {
            const float4* xp = (const float4*)&x[(size_t)(pt0p + rt * 16 + col) * FEAT + kh * 32 + q * 8];
            float4 v0 = xp[0], v1 = xp[1];
            frag_ab a;
            a[0] = f2bf(v0.x); a[1] = f2bf(v0.y); a[2] = f2bf(v0.z); a[3] = f2bf(v0.w);
            a[4] = f2bf(v1.x); a[5] = f2bf(v1.y); a[6] = f2bf(v1.z); a[7] = f2bf(v1.w);
            A4[rt][kh] = a;
            ps = fmaf(v0.x, v0.x, ps); ps = fmaf(v0.y, v0.y, ps);
            ps = fmaf(v0.z, v0.z, ps); ps = fmaf(v0.w, v0.w, ps);
            ps = fmaf(v1.x, v1.x, ps); ps = fmaf(v1.y, v1.y, ps);
            ps = fmaf(v1.z, v1.z, ps); ps = fmaf(v1.w, v1.w, ps);
        }
        ps += __shfl_xor(ps, 16);
        ps += __shfl_xor(ps, 32);
        nrm4[rt] = sqrtf(ps);
    }

    float m4[4][4];
#pragma unroll
    for (int rt = 0; rt < 4; ++rt)
#pragma unroll
        for (int r = 0; r < 4; ++r) m4[rt][r] = INFINITY;

    frag_ab pre[8];
    float   cnpre;

    // ------------------- PASS 1: approx min, pair-cooperative --------------
    load_chunk(cbs_t, cnorm, 0, tid, pre, &cnpre);
    for (int c8 = 0; c8 < NCHUNK; ++c8) {
        __syncthreads();
#pragma unroll
        for (int p8 = 0; p8 < 8; ++p8)
            *(frag_ab*)&csh[(p8 * CHUNKC + tid) * 8] = pre[p8];
        cnsh[tid] = cnpre;
        __syncthreads();
        if (c8 < NCHUNK - 1)
            load_chunk(cbs_t, cnorm, (c8 + 1) * CHUNKC, tid, pre, &cnpre);  // overlaps compute

#pragma unroll 4
        for (int ct = 0; ct < CHUNKC / 32; ++ct) {          // 8 col-groups (own half)
            const int lc = h * 128 + ct * 16 + col;
            frag_ab b0 = *(const frag_ab*)&csh[(q * CHUNKC + lc) * 8];
            frag_ab b1 = *(const frag_ab*)&csh[((4 + q) * CHUNKC + lc) * 8];
            const float cnv = cnsh[lc];
#pragma unroll
            for (int rt = 0; rt < 4; ++rt) {
                frag_cd acc = {cnv, cnv, cnv, cnv};
                acc = __builtin_amdgcn_mfma_f32_16x16x32_bf16(A4[rt][0], b0, acc, 0, 0, 0);
                acc = __builtin_amdgcn_mfma_f32_16x16x32_bf16(A4[rt][1], b1, acc, 0, 0, 0);
                m4[rt][0] = fminf(m4[rt][0], acc[0]);
                m4[rt][1] = fminf(m4[rt][1], acc[1]);
                m4[rt][2] = fminf(m4[rt][2], acc[2]);
                m4[rt][3] = fminf(m4[rt][3], acc[3]);
            }
        }
    }

    // ----- exchange per-lane minima with partner wave via csh (now free) ---
    // Transposed scalar layout: value v at mx[v*256 + tid] -> lanes write/read
    // consecutive addresses -> conflict-free.  16 KB of the 32 KB csh.
    __syncthreads();                       // all waves done reading chunk 7
    {
        float* mx = (float*)csh;
#pragma unroll
        for (int rt = 0; rt < 4; ++rt)
#pragma unroll
            for (int r = 0; r < 4; ++r)
                mx[(rt * 4 + r) * 256 + tid] = m4[rt][r];
    }
    __syncthreads();
    {
        const float* mx = (const float*)csh;
        const int ptid = tid ^ 64;         // partner wave, same lane
#pragma unroll
        for (int rt = 0; rt < 4; ++rt)
#pragma unroll
            for (int r = 0; r < 4; ++r)
                m4[rt][r] = fminf(m4[rt][r], mx[(rt * 4 + r) * 256 + ptid]);
    }

    // ----- wave-uniform COMPILE-TIME selection of this wave's pass-2 state --
    frag_ab A2[2][2];
    float   nrm2[2];
    float   m2[2][4];
    if (h == 0) {
        A2[0][0] = A4[0][0]; A2[0][1] = A4[0][1];
        A2[1][0] = A4[1][0]; A2[1][1] = A4[1][1];
        nrm2[0] = nrm4[0]; nrm2[1] = nrm4[1];
#pragma unroll
        for (int r = 0; r < 4; ++r) { m2[0][r] = m4[0][r]; m2[1][r] = m4[1][r]; }
    } else {
        A2[0][0] = A4[2][0]; A2[0][1] = A4[2][1];
        A2[1][0] = A4[3][0]; A2[1][1] = A4[3][1];
        nrm2[0] = nrm4[2]; nrm2[1] = nrm4[3];
#pragma unroll
        for (int r = 0; r < 4; ++r) { m2[0][r] = m4[2][r]; m2[1][r] = m4[3][r]; }
    }

    // Threshold: m~ + 0.034*||x||*cmax >= m~ + 2*eps_bf16 (proven margin).
    const float cmax = *cmaxp;
    float t[2][4];
#pragma unroll
    for (int rt = 0; rt < 2; ++rt)
#pragma unroll
        for (int r = 0; r < 4; ++r) {
            float mm = m2[rt][r];
            mm = fminf(mm, __shfl_xor(mm, 1));
            mm = fminf(mm, __shfl_xor(mm, 2));
            mm = fminf(mm, __shfl_xor(mm, 4));
            mm = fminf(mm, __shfl_xor(mm, 8));
            float xnp = __shfl(nrm2[rt], q * 4 + r);   // lane q*4+r holds that row's norm
            t[rt][r] = mm + 0.034f * xnp * cmax;
        }

    // ------------------- PASS 2: per-lane register capture (r0 verbatim) ---
    unsigned codes[CANDC];
    int ccnt = 0;

    load_chunk(cbs_t, cnorm, 0, tid, pre, &cnpre);
    for (int c8 = 0; c8 < NCHUNK; ++c8) {
        __syncthreads();
#pragma unroll
        for (int p8 = 0; p8 < 8; ++p8)
            *(frag_ab*)&csh[(p8 * CHUNKC + tid) * 8] = pre[p8];
        cnsh[tid] = cnpre;
        __syncthreads();
        if (c8 < NCHUNK - 1)
            load_chunk(cbs_t, cnorm, (c8 + 1) * CHUNKC, tid, pre, &cnpre);

        const int k0 = c8 * CHUNKC;
#pragma unroll 2
        for (int ct = 0; ct < CHUNKC / 16; ++ct) {
            const int lc = ct * 16 + col;
            frag_ab b0 = *(const frag_ab*)&csh[(q * CHUNKC + lc) * 8];
            frag_ab b1 = *(const frag_ab*)&csh[((4 + q) * CHUNKC + lc) * 8];
            const float cnv = cnsh[lc];
            const int kk = k0 + lc;
#pragma unroll
            for (int rt = 0; rt < 2; ++rt) {
                frag_cd acc = {cnv, cnv, cnv, cnv};
                acc = __builtin_amdgcn_mfma_f32_16x16x32_bf16(A2[rt][0], b0, acc, 0, 0, 0);
                acc = __builtin_amdgcn_mfma_f32_16x16x32_bf16(A2[rt][1], b1, acc, 0, 0, 0);
#pragma unroll
                for (int r = 0; r < 4; ++r) {
                    if (acc[r] <= t[rt][r]) {   // rare
                        unsigned code = ((unsigned)(rt * 16 + q * 4 + r) << 11) | (unsigned)kk;
#pragma unroll
                        for (int s = 0; s < CANDC; ++s)   // register-file push
                            if (s == ccnt) codes[s] = code;
                        ccnt++;
                    }
                }
            }
        }
    }

    // ------------------- exact refine (per-lane, registers) ----------------
    const bool anyovf = __any(ccnt > CANDC);

    if (!anyovf) {
        float bestd[2][4];
        int   bestk[2][4];
#pragma unroll
        for (int rt = 0; rt < 2; ++rt)
#pragma unroll
            for (int r = 0; r < 4; ++r) { bestd[rt][r] = INFINITY; bestk[rt][r] = 0x7fffffff; }

        for (int i = 0; i < CANDC; ++i) {
            if (i < ccnt) {
                unsigned code = codes[i];
                int pl = (int)(code >> 11), kk = (int)(code & 2047u);
                float e = exact_dist(x, c, cnorm[kk], pt0 + pl, kk);
                int crt = pl >> 4, cr = pl & 3;
#pragma unroll
                for (int rt = 0; rt < 2; ++rt)
#pragma unroll
                    for (int r = 0; r < 4; ++r)
                        if (crt == rt && cr == r &&
                            (e < bestd[rt][r] || (e == bestd[rt][r] && kk < bestk[rt][r]))) {
                            bestd[rt][r] = e; bestk[rt][r] = kk;
                        }
            }
        }

        // Proven cross-lane (d,k) reduce + col==0 writes (float4 + ushort4).
#pragma unroll
        for (int rt = 0; rt < 2; ++rt) {
#pragma unroll
            for (int r = 0; r < 4; ++r) {
                float bd = bestd[rt][r]; int bk = bestk[rt][r];
#pragma unroll
                for (int mask = 1; mask <= 8; mask <<= 1) {
                    float od = __shfl_xor(bd, mask);
                    int   ok = __shfl_xor(bk, mask);
                    if (od < bd || (od == bd && ok < bk)) { bd = od; bk = ok; }
                }
                bestd[rt][r] = bd; bestk[rt][r] = bk;
            }
            if (col == 0) {
                float4 w = { (float)bestk[rt][0], (float)bestk[rt][1],
                             (float)bestk[rt][2], (float)bestk[rt][3] };
                *(float4*)&out_assign[pt0 + rt * 16 + q * 4] = w;
                ushort4 u = { (unsigned short)bestk[rt][0], (unsigned short)bestk[rt][1],
                              (unsigned short)bestk[rt][2], (unsigned short)bestk[rt][3] };
                *(ushort4*)&a16[pt0 + rt * 16 + q * 4] = u;
            }
        }
    } else {
        // Overflow (rare): whole-wave fully-exact argmin, no thresholds.
        for (int pp = 0; pp < PPW; ++pp) {
            const int p = pt0 + pp;
            float bd = INFINITY; int bk = 0x7fffffff;
            for (int kk = lane; kk < KCLUS; kk += 64) {
                float e = exact_dist(x, c, cnorm[kk], p, kk);
                if (e < bd || (e == bd && kk < bk)) { bd = e; bk = kk; }
            }
#pragma unroll
            for (int mask = 1; mask <= 32; mask <<= 1) {
                float od = __shfl_xor(bd, mask);
                int   ok = __shfl_xor(bk, mask);
                if (od < bd || (od == bd && ok < bk)) { bd = od; bk = ok; }
            }
            if (lane == 0) {
                out_assign[p] = (float)bk;
                a16[p] = (unsigned short)bk;
            }
        }
    }
}

// ---------------------------------------------------------------------------
// Scatter (proven, verbatim): block (cg, slice) owns clusters [8cg,8cg+8)
// over point slice [slice*16384, +16384). Ballot-collect, per-wave LDS
// accumulate, 8 atomic rows per block.
// ---------------------------------------------------------------------------
__global__ void scatter_kernel(const float* __restrict__ x,
                               const unsigned short* __restrict__ a16,
                               float* __restrict__ sums, int* __restrict__ counts) {
    __shared__ float wsum[4][8][64];   // 8 KB, per-wave private
    __shared__ int   wcnt[4][8];

    const int tid = threadIdx.x, wv = tid >> 6, lane = tid & 63;
    const int c0 = blockIdx.x * 8;

    for (int idx = tid; idx < 4 * 8 * 64; idx += 256) ((float*)wsum)[idx] = 0.f;
    if (tid < 32) ((int*)wcnt)[tid] = 0;
    __syncthreads();

    const int base = blockIdx.y * 16384 + wv * 4096;
#pragma unroll 1
    for (int it = 0; it < 64; ++it) {
        const int pbase = base + it * 64;
        int a = (int)a16[pbase + lane];                    // coalesced 128B
        unsigned long long mask = __ballot(a >= c0 && a < c0 + 8);
        while (mask) {
            int j = __ffsll((long long)mask) - 1;
            mask &= mask - 1;
            int cl = __shfl(a, j) - c0;
            float xv = x[(size_t)(pbase + j) * FEAT + lane];  // coalesced 256B row
            wsum[wv][cl][lane] += xv;                         // own slice: no race
            if (lane == 0) wcnt[wv][cl] += 1;
        }
    }
    __syncthreads();

    for (int idx = tid; idx < 512; idx += 256) {
        int cl = idx >> 6, ln = idx & 63;
        float s = wsum[0][cl][ln] + wsum[1][cl][ln] + wsum[2][cl][ln] + wsum[3][cl][ln];
        atomicAdd(&sums[(size_t)(c0 + cl) * FEAT + ln], s);
    }
    if (tid < 8) {
        int cc = wcnt[0][tid] + wcnt[1][tid] + wcnt[2][tid] + wcnt[3][tid];
        if (cc) atomicAdd(&counts[c0 + tid], cc);
    }
}

__global__ void update_kernel(const float* __restrict__ c,
                              const float* __restrict__ sums,
                              const int* __restrict__ counts,
                              float* __restrict__ out_upd) {
    int i = blockIdx.x * blockDim.x + threadIdx.x;
    if (i < KCLUS * FEAT) {
        int   k   = i >> 6;
        float cv  = c[i];
        int   cnt = counts[k];
        float nc  = (cnt > 0) ? (sums[i] / (float)cnt) : cv;
        out_upd[i] = 0.99f * cv + 0.01f * nc;
    }
}

extern "C" void kernel_launch(void* const* d_in, const int* in_sizes, int n_in,
                              void* d_out, int out_size, void* d_ws, size_t ws_size,
                              hipStream_t stream) {
    const float* x = (const float*)d_in[0];
    const float* c = (const float*)d_in[1];

    float* out        = (float*)d_out;
    float* out_assign = out;          // [0, N): assignments as float
    float* out_upd    = out + NPTS;   // [N, N + K*FEAT)

    // Workspace ~1.06 MB.
    char* ws = (char*)d_ws;
    constexpr size_t O_CNORM = 0;                       // 8 KB
    constexpr size_t O_CBS   = 8192;                    // 256 KB
    constexpr size_t O_ZERO  = 8192 + 262144;           // 270336
    constexpr size_t O_CMAX  = O_ZERO;                  // 64 B
    constexpr size_t O_SUMS  = O_ZERO + 64;             // 512 KB
    constexpr size_t O_CNTS  = O_SUMS + 524288;         // 8 KB
    constexpr size_t ZERO_LEN = 64 + 524288 + 8192;     // 532544
    constexpr size_t O_A16   = O_ZERO + ZERO_LEN;       // 802880, 256 KB

    float*    cnorm  = (float*)(ws + O_CNORM);
    short*    cbs_t  = (short*)(ws + O_CBS);
    float*    cmax   = (float*)(ws + O_CMAX);
    float*    sums   = (float*)(ws + O_SUMS);
    int*      counts = (int*)(ws + O_CNTS);
    unsigned short* a16 = (unsigned short*)(ws + O_A16);

    hipMemsetAsync(ws + O_ZERO, 0, ZERO_LEN, stream);

    cprep_kernel<<<KCLUS / 256, 256, 0, stream>>>(c, cnorm, cbs_t, cmax);
    // 4 waves/block x 32 pts/wave = 128 pts/block -> grid 1024 (4 blocks/CU)
    assign_kernel<<<NPTS / PPB, 256, 0, stream>>>(x, c, cbs_t, cnorm, cmax,
                                                  out_assign, a16);
    scatter_kernel<<<dim3(KCLUS / 8, 8), 256, 0, stream>>>(x, a16, sums, counts);
    update_kernel<<<(KCLUS * FEAT) / 256, 256, 0, stream>>>(c, sums, counts, out_upd);
}